// Round 6
// baseline (371.731 us; speedup 1.0000x reference)
//
#include <hip/hip_runtime.h>
#include <stdint.h>
#include <math.h>

#define NB   16
#define CIN  8192
#define CHID 512
#define COUT 100
#define TT   300
#define TG4  4
#define NTG4 75    // 300/4
#define CAP1 96    // per-(b,t,seg) list cap, layer 1 (mean 20.5, sigma 4.5 -> 16.8 sigma)
#define CAP2 64    // layers 2/3: full seg range, cannot overflow

// ---------------- row norms: nrm[row] = sqrt(sum v[row][i]^2) ----------------
__global__ void norm_kernel(const float* __restrict__ v, float* __restrict__ nrm, int cin) {
    int row = blockIdx.x;
    const float* vr = v + (size_t)row * cin;
    float s = 0.f;
    for (int i = threadIdx.x; i < cin; i += 256) {
        float x = vr[i];
        s = __fadd_rn(s, __fmul_rn(x, x));
    }
    __shared__ float red[256];
    red[threadIdx.x] = s;
    __syncthreads();
    for (int off = 128; off > 0; off >>= 1) {
        if (threadIdx.x < off) red[threadIdx.x] += red[threadIdx.x + off];
        __syncthreads();
    }
    if (threadIdx.x == 0) nrm[row] = sqrtf(red[0]);
}

// ------------- transpose + weight-norm scale: wt[i][o] = (v[o][i]*g[o])/nrm[o] -------------
template<int WS>
__global__ void trans_kernel(const float* __restrict__ v, const float* __restrict__ g,
                             const float* __restrict__ nrm, float* __restrict__ wt,
                             int RO, int CI) {
    __shared__ float tile[32][33];
    int i0 = blockIdx.x * 32, o0 = blockIdx.y * 32;
    int tx = threadIdx.x, ty = threadIdx.y;
    for (int k = 0; k < 32; k += 8) {
        int o = o0 + ty + k, i = i0 + tx;
        float val = 0.f;
        if (o < RO) val = __fmul_rn(v[(size_t)o * CI + i], g[o]) / nrm[o];
        tile[ty + k][tx] = val;
    }
    __syncthreads();
    for (int k = 0; k < 32; k += 8) {
        int i = i0 + ty + k, oo = o0 + tx;
        if (oo < WS) wt[(size_t)i * WS + oo] = tile[tx][ty + k];
    }
}

// ------------- layer-1 event build: spike fp32 -> per-(b,t,seg) u16 lists -------------
// Block (b, tg of 4 t), 256 thr. Wave wv builds segments 2wv,2wv+1 (1024 i each):
// ballot-compacted, i-ascending, written straight to global. Deterministic.
__global__ __launch_bounds__(256) void evbuild1_kernel(const float* __restrict__ spike,
                                                       uint16_t* __restrict__ ev,
                                                       int* __restrict__ cnt) {
    int b = blockIdx.x, tg = blockIdx.y, t0 = tg * TG4;
    int tid = threadIdx.x, lane = tid & 63, wv = tid >> 6;
    for (int ss = 0; ss < 2; ++ss) {
        int s = wv * 2 + ss;
        int cl[4] = {0, 0, 0, 0};
        for (int c = 0; c < 16; ++c) {   // 1024/64 chunks
            int i = s * 1024 + c * 64 + lane;
            const float* sp = spike + ((size_t)(b * CIN + i)) * TT + t0;
            float4 v4 = *(const float4*)sp;   // row stride 1200B, t0*4%16==0 -> aligned
            uint32_t m = 0;
            m |= (v4.x != 0.f) ? 1u : 0u;
            m |= (v4.y != 0.f) ? 2u : 0u;
            m |= (v4.z != 0.f) ? 4u : 0u;
            m |= (v4.w != 0.f) ? 8u : 0u;
            #pragma unroll
            for (int t = 0; t < 4; ++t) {
                uint32_t bit = (m >> t) & 1u;
                uint64_t bal = __ballot(bit != 0);
                int pos = __popcll(bal & ((1ull << lane) - 1ull));
                if (bit) {
                    int p = cl[t] + pos;
                    if (p < CAP1)
                        ev[(((size_t)b * TT + t0 + t) * 8 + s) * CAP1 + p] = (uint16_t)i;
                }
                cl[t] += (int)__popcll(bal);
                if (cl[t] > CAP1) cl[t] = CAP1;
            }
        }
        if (lane == 0) {
            #pragma unroll
            for (int t = 0; t < 4; ++t)
                cnt[((size_t)b * TT + t0 + t) * 8 + s] = cl[t];
        }
    }
}

// ------------- XCD-sliced gather: z[b][t][o] = sum_segs sum_{i in list} wt[i][o] -------------
// Grid (NSLICE, 16 b, 75 tg), 256 thr = 4 waves; wave = one t, lane covers one output
// (dword loads, 256B/wave). gridDim.x slices * 64 outputs; linear bid % 8 keyed by slice
// -> per-XCD wt working set = 64*NI*4B (2MB layer1) stays L2-resident.
// Walk order: seg ascending, j ascending == exact i-ascending sums.
template<int WS, int CAP>
__global__ __launch_bounds__(256) void zg_kernel(const uint16_t* __restrict__ ev,
                                                 const int* __restrict__ cnt,
                                                 const float* __restrict__ wt,
                                                 float* __restrict__ zout) {
    int oslice = blockIdx.x, b = blockIdx.y, tg = blockIdx.z;
    int tid = threadIdx.x, lane = tid & 63, wv = tid >> 6;
    int t = tg * TG4 + wv;
    int obase = oslice * 64 + lane;
    size_t bt = (size_t)b * TT + t;
    const uint16_t* erow = ev + bt * (8 * CAP);
    const int* crow = cnt + bt * 8;
    const float* wp = wt + obase;
    float acc = 0.f;
    for (int s = 0; s < 8; ++s) {
        int n = crow[s];
        const uint16_t* lp = erow + s * CAP;
        int j = 0;
        for (; j + 8 <= n; j += 8) {
            uint4 g = *(const uint4*)(lp + j);   // 16B-aligned broadcast
            uint32_t e0 = g.x & 0xFFFFu, e1 = g.x >> 16;
            uint32_t e2 = g.y & 0xFFFFu, e3 = g.y >> 16;
            uint32_t e4 = g.z & 0xFFFFu, e5 = g.z >> 16;
            uint32_t e6 = g.w & 0xFFFFu, e7 = g.w >> 16;
            float w0 = wp[(size_t)e0 * WS];
            float w1 = wp[(size_t)e1 * WS];
            float w2 = wp[(size_t)e2 * WS];
            float w3 = wp[(size_t)e3 * WS];
            float w4 = wp[(size_t)e4 * WS];
            float w5 = wp[(size_t)e5 * WS];
            float w6 = wp[(size_t)e6 * WS];
            float w7 = wp[(size_t)e7 * WS];
            acc += w0; acc += w1; acc += w2; acc += w3;
            acc += w4; acc += w5; acc += w6; acc += w7;
        }
        for (; j < n; ++j)
            acc += wp[(size_t)lp[j] * WS];
    }
    zout[bt * WS + obase] = acc;
}

// ------- CUBA-LIF scan (hidden): consumes z, emits per-(b,t,oseg) u16 event lists -------
// Block = (b, oseg): 64 threads = 1 wave, o = oseg*64+lane. Pipelined z loads (A/B, groups
// of 10, static indices). Per t: ballot-compact spikes into global list (o-ascending).
__global__ __launch_bounds__(64) void lif_ev_kernel(const float* __restrict__ z,
                                                    uint16_t* __restrict__ ev,
                                                    int* __restrict__ cnt,
                                                    const float* __restrict__ cdarr,
                                                    const float* __restrict__ vdarr,
                                                    int li) {
    int bid = blockIdx.x;
    int b = bid >> 3, oseg = bid & 7;
    int lane = threadIdx.x;
    int o = oseg * 64 + lane;
    float omc = 1.0f - cdarr[li];
    float omv = 1.0f - vdarr[li];
    float cur = 0.f, volt = 0.f;
    const float* zp = z + (size_t)b * TT * CHID + o;
    uint64_t ltmask = (1ull << lane) - 1ull;

    float A[10], Bv[10];
    auto loadg = [&](float (&buf)[10], int g) {
        #pragma unroll
        for (int k = 0; k < 10; ++k) buf[k] = zp[(size_t)(g * 10 + k) * CHID];
    };
    auto stepg = [&](float (&buf)[10], int g) {
        #pragma unroll
        for (int k = 0; k < 10; ++k) {
            int t = g * 10 + k;
            cur  = __fadd_rn(__fmul_rn(omc, cur), buf[k]);
            volt = __fadd_rn(__fmul_rn(omv, volt), cur);
            bool s = (volt >= 1.25f);
            volt = s ? 0.f : volt;
            uint64_t bal = __ballot(s);
            int pos = (int)__popcll(bal & ltmask);
            size_t base = ((size_t)b * TT + t) * 8 + oseg;
            if (s) ev[base * CAP2 + pos] = (uint16_t)o;
            if (lane == 0) cnt[base] = (int)__popcll(bal);
        }
    };
    loadg(A, 0);
    for (int g = 0; g < 30; g += 2) {
        if (g + 1 < 30) loadg(Bv, g + 1);
        stepg(A, g);
        if (g + 2 < 30) loadg(A, g + 2);
        if (g + 1 < 30) stepg(Bv, g + 1);
    }
}

// ---------------- CUBA-LIF final layer -> d_out [B][COUT][T] float, pipelined ----------------
__global__ __launch_bounds__(64) void lif_out_kernel(const float* __restrict__ z,
                                                     float* __restrict__ out,
                                                     const float* __restrict__ cdarr,
                                                     const float* __restrict__ vdarr,
                                                     int li) {
    int gid = blockIdx.x * 64 + threadIdx.x;
    if (gid >= NB * COUT) return;
    int b = gid / COUT, o = gid % COUT;
    float omc = 1.0f - cdarr[li];
    float omv = 1.0f - vdarr[li];
    float cur = 0.f, volt = 0.f;
    const float* zp = z + (size_t)b * TT * 128 + o;
    float* op = out + ((size_t)b * COUT + o) * TT;

    float A[10], Bv[10];
    auto loadg = [&](float (&buf)[10], int g) {
        #pragma unroll
        for (int k = 0; k < 10; ++k) buf[k] = zp[(size_t)(g * 10 + k) * 128];
    };
    auto stepg = [&](float (&buf)[10], int g) {
        #pragma unroll
        for (int k = 0; k < 10; ++k) {
            cur  = __fadd_rn(__fmul_rn(omc, cur), buf[k]);
            volt = __fadd_rn(__fmul_rn(omv, volt), cur);
            bool s = (volt >= 1.25f);
            volt = s ? 0.f : volt;
            op[g * 10 + k] = s ? 1.0f : 0.0f;
        }
    };
    loadg(A, 0);
    for (int g = 0; g < 30; g += 2) {
        if (g + 1 < 30) loadg(Bv, g + 1);
        stepg(A, g);
        if (g + 2 < 30) loadg(A, g + 2);
        if (g + 1 < 30) stepg(Bv, g + 1);
    }
}

extern "C" void kernel_launch(void* const* d_in, const int* in_sizes, int n_in,
                              void* d_out, int out_size, void* d_ws, size_t ws_size,
                              hipStream_t stream) {
    const float* spike = (const float*)d_in[0];
    const float* v1 = (const float*)d_in[1];
    const float* g1 = (const float*)d_in[2];
    const float* v2 = (const float*)d_in[3];
    const float* g2 = (const float*)d_in[4];
    const float* v3 = (const float*)d_in[5];
    const float* g3 = (const float*)d_in[6];
    const float* cd = (const float*)d_in[7];
    const float* vd = (const float*)d_in[8];

    // workspace layout
    float* ws   = (float*)d_ws;
    float* w1t  = ws;                            // [8192][512]
    float* w2t  = w1t + (size_t)CIN * CHID;      // [512][512]
    float* w3t  = w2t + (size_t)CHID * CHID;     // [512][128]
    float* nrm1 = w3t + (size_t)CHID * 128;      // 512
    float* nrm2 = nrm1 + 512;                    // 512
    float* nrm3 = nrm2 + 512;                    // 128
    float* zbuf = nrm3 + 128;                    // [16][300][512] (z1 then z2)
    float* z3   = zbuf + (size_t)NB * TT * CHID; // [16][300][128]
    // ev/cnt region shared by all three layers (sequential lifetimes:
    // evbuild1->zg1 reads ev1; lif_ev(0) overwrites with ev2 after zg1; etc.)
    uint16_t* evb  = (uint16_t*)(z3 + (size_t)NB * TT * 128);      // [16][300][8][CAP1]
    int*      cntb = (int*)(evb + (size_t)NB * TT * 8 * CAP1);     // [16][300][8]
    size_t need = (size_t)((uint8_t*)(cntb + (size_t)NB * TT * 8) - (uint8_t*)d_ws);
    if (ws_size < need) return;  // fail loudly via wrong output rather than corrupt

    // weight prep
    norm_kernel<<<dim3(CHID), dim3(256), 0, stream>>>(v1, nrm1, CIN);
    norm_kernel<<<dim3(CHID), dim3(256), 0, stream>>>(v2, nrm2, CHID);
    norm_kernel<<<dim3(COUT), dim3(256), 0, stream>>>(v3, nrm3, CHID);
    trans_kernel<512><<<dim3(CIN / 32, CHID / 32), dim3(32, 8), 0, stream>>>(v1, g1, nrm1, w1t, CHID, CIN);
    trans_kernel<512><<<dim3(CHID / 32, CHID / 32), dim3(32, 8), 0, stream>>>(v2, g2, nrm2, w2t, CHID, CHID);
    trans_kernel<128><<<dim3(CHID / 32, 4), dim3(32, 8), 0, stream>>>(v3, g3, nrm3, w3t, COUT, CHID);

    // layer 1
    evbuild1_kernel<<<dim3(NB, NTG4), dim3(256), 0, stream>>>(spike, evb, cntb);
    zg_kernel<512, CAP1><<<dim3(8, NB, NTG4), dim3(256), 0, stream>>>(evb, cntb, w1t, zbuf);
    lif_ev_kernel<<<dim3(NB * 8), dim3(64), 0, stream>>>(zbuf, evb, cntb, cd, vd, 0);
    // layer 2 (lists now CAP2-strided; lif_ev wrote them that way)
    zg_kernel<512, CAP2><<<dim3(8, NB, NTG4), dim3(256), 0, stream>>>(evb, cntb, w2t, zbuf);
    lif_ev_kernel<<<dim3(NB * 8), dim3(64), 0, stream>>>(zbuf, evb, cntb, cd, vd, 1);
    // layer 3
    zg_kernel<128, CAP2><<<dim3(2, NB, NTG4), dim3(256), 0, stream>>>(evb, cntb, w3t, z3);
    lif_out_kernel<<<dim3((NB * COUT + 63) / 64), dim3(64), 0, stream>>>(z3, (float*)d_out, cd, vd, 2);
}

// Round 7
// 267.838 us; speedup vs baseline: 1.3879x; 1.3879x over previous
//
#include <hip/hip_runtime.h>
#include <stdint.h>
#include <math.h>

#define NB   16
#define CIN  8192
#define CHID 512
#define COUT 100
#define TT   300
#define TG4  4
#define NTG4 75     // 300/4
#define SEGCAP 96   // per-(seg,t) LDS cap, layer1 (mean 20.5, sigma 4.5 -> 16.8 sigma)
#define EVCAP1 384  // merged per-(b,t) cap, layer1 (mean 164, sigma 12.7 -> 17 sigma)
#define EVCAP2 512  // layers 2/3: full range, cannot overflow

// ---------------- row norms: nrm[row] = sqrt(sum v[row][i]^2) ----------------
__global__ void norm_kernel(const float* __restrict__ v, float* __restrict__ nrm, int cin) {
    int row = blockIdx.x;
    const float* vr = v + (size_t)row * cin;
    float s = 0.f;
    for (int i = threadIdx.x; i < cin; i += 256) {
        float x = vr[i];
        s = __fadd_rn(s, __fmul_rn(x, x));
    }
    __shared__ float red[256];
    red[threadIdx.x] = s;
    __syncthreads();
    for (int off = 128; off > 0; off >>= 1) {
        if (threadIdx.x < off) red[threadIdx.x] += red[threadIdx.x + off];
        __syncthreads();
    }
    if (threadIdx.x == 0) nrm[row] = sqrtf(red[0]);
}

// ------------- transpose + weight-norm scale: wt[i][o] = (v[o][i]*g[o])/nrm[o] -------------
template<int WS>
__global__ void trans_kernel(const float* __restrict__ v, const float* __restrict__ g,
                             const float* __restrict__ nrm, float* __restrict__ wt,
                             int RO, int CI) {
    __shared__ float tile[32][33];
    int i0 = blockIdx.x * 32, o0 = blockIdx.y * 32;
    int tx = threadIdx.x, ty = threadIdx.y;
    for (int k = 0; k < 32; k += 8) {
        int o = o0 + ty + k, i = i0 + tx;
        float val = 0.f;
        if (o < RO) val = __fmul_rn(v[(size_t)o * CI + i], g[o]) / nrm[o];
        tile[ty + k][tx] = val;
    }
    __syncthreads();
    for (int k = 0; k < 32; k += 8) {
        int i = i0 + ty + k, oo = o0 + tx;
        if (oo < WS) wt[(size_t)i * WS + oo] = tile[tx][ty + k];
    }
}

// ------------- layer-1 event build: spike fp32 -> merged per-(b,t) u32 offset lists -------------
// Block (b, tg of 4 t), 256 thr. Phase 1: wave wv ballot-compacts segments 2wv,2wv+1
// (1024 i each) into LDS, entries pre-shifted (i*2048 = byte offset into wt row).
// Phase 2: wave t merges the 8 segment lists contiguously to global (i-ascending).
__global__ __launch_bounds__(256) void evbuild1_kernel(const float* __restrict__ spike,
                                                       uint32_t* __restrict__ ev,
                                                       int* __restrict__ cnt) {
    __shared__ uint32_t act[4][8][SEGCAP];
    __shared__ int      c_lds[4][8];
    int b = blockIdx.x, tg = blockIdx.y, t0 = tg * TG4;
    int tid = threadIdx.x, lane = tid & 63, wv = tid >> 6;
    for (int ss = 0; ss < 2; ++ss) {
        int s = wv * 2 + ss;
        int cl[4] = {0, 0, 0, 0};
        for (int c = 0; c < 16; ++c) {
            int i = s * 1024 + c * 64 + lane;
            const float* sp = spike + ((size_t)(b * CIN + i)) * TT + t0;
            float4 v4 = *(const float4*)sp;   // row stride 1200B, t0*4%16==0 -> aligned
            uint32_t m = 0;
            m |= (v4.x != 0.f) ? 1u : 0u;
            m |= (v4.y != 0.f) ? 2u : 0u;
            m |= (v4.z != 0.f) ? 4u : 0u;
            m |= (v4.w != 0.f) ? 8u : 0u;
            #pragma unroll
            for (int t = 0; t < 4; ++t) {
                uint32_t bit = (m >> t) & 1u;
                uint64_t bal = __ballot(bit != 0);
                int pos = __popcll(bal & ((1ull << lane) - 1ull));
                if (bit) {
                    int p = cl[t] + pos;
                    if (p < SEGCAP) act[t][s][p] = (uint32_t)i << 11;   // i*2048 bytes
                }
                cl[t] += (int)__popcll(bal);
                if (cl[t] > SEGCAP) cl[t] = SEGCAP;
            }
        }
        if (lane == 0) {
            #pragma unroll
            for (int t = 0; t < 4; ++t) c_lds[t][s] = cl[t];
        }
    }
    __syncthreads();
    if (wv < 4) {   // wave wv merges timestep t0+wv
        int t = t0 + wv;
        uint32_t* erow = ev + ((size_t)b * TT + t) * EVCAP1;
        int off = 0;
        for (int s = 0; s < 8; ++s) {
            int c = c_lds[wv][s];
            for (int p = lane; p < c; p += 64)
                if (off + p < EVCAP1) erow[off + p] = act[wv][s][p];
            off += c;
        }
        if (lane == 0) cnt[(size_t)b * TT + t] = off < EVCAP1 ? off : EVCAP1;
    }
}

// ------------- XCD-sliced gather: z[b][t][o] = sum_{off in evlist(b,t)} wt_row(off)[o] -------------
// Grid (NSLICE, 16 b, 75 tg), 256 thr = 4 waves; wave = one t, lane = one output.
// Linear bid % 8 keyed by slice -> per-XCD wt working set = 64 cols * NI rows * 4B
// (2MB layer1) stays L2-resident. Entries are pre-shifted byte offsets; walk order
// j-ascending == i-ascending (exact sums, same order as all prior passing rounds).
template<int WS, int EVCAP>
__global__ __launch_bounds__(256) void zg_kernel(const uint32_t* __restrict__ ev,
                                                 const int* __restrict__ cnt,
                                                 const float* __restrict__ wt,
                                                 float* __restrict__ zout) {
    int oslice = blockIdx.x, b = blockIdx.y, tg = blockIdx.z;
    int tid = threadIdx.x, lane = tid & 63, wv = tid >> 6;
    int t = tg * TG4 + wv;
    size_t bt = (size_t)b * TT + t;
    const uint32_t* erow = ev + bt * EVCAP;
    int n = cnt[bt];
    const char* wb = (const char*)wt + (size_t)oslice * 256;  // uniform (SGPR) base
    uint32_t lane4 = (uint32_t)lane * 4u;
    float acc = 0.f;
    int j = 0;
    for (; j + 16 <= n; j += 16) {
        uint4 eA = *(const uint4*)(erow + j);
        uint4 eB = *(const uint4*)(erow + j + 4);
        uint4 eC = *(const uint4*)(erow + j + 8);
        uint4 eD = *(const uint4*)(erow + j + 12);
        float w0  = *(const float*)(wb + (size_t)(eA.x + lane4));
        float w1  = *(const float*)(wb + (size_t)(eA.y + lane4));
        float w2  = *(const float*)(wb + (size_t)(eA.z + lane4));
        float w3  = *(const float*)(wb + (size_t)(eA.w + lane4));
        float w4  = *(const float*)(wb + (size_t)(eB.x + lane4));
        float w5  = *(const float*)(wb + (size_t)(eB.y + lane4));
        float w6  = *(const float*)(wb + (size_t)(eB.z + lane4));
        float w7  = *(const float*)(wb + (size_t)(eB.w + lane4));
        float w8  = *(const float*)(wb + (size_t)(eC.x + lane4));
        float w9  = *(const float*)(wb + (size_t)(eC.y + lane4));
        float w10 = *(const float*)(wb + (size_t)(eC.z + lane4));
        float w11 = *(const float*)(wb + (size_t)(eC.w + lane4));
        float w12 = *(const float*)(wb + (size_t)(eD.x + lane4));
        float w13 = *(const float*)(wb + (size_t)(eD.y + lane4));
        float w14 = *(const float*)(wb + (size_t)(eD.z + lane4));
        float w15 = *(const float*)(wb + (size_t)(eD.w + lane4));
        acc += w0;  acc += w1;  acc += w2;  acc += w3;
        acc += w4;  acc += w5;  acc += w6;  acc += w7;
        acc += w8;  acc += w9;  acc += w10; acc += w11;
        acc += w12; acc += w13; acc += w14; acc += w15;
    }
    for (; j + 4 <= n; j += 4) {
        uint4 e = *(const uint4*)(erow + j);
        float w0 = *(const float*)(wb + (size_t)(e.x + lane4));
        float w1 = *(const float*)(wb + (size_t)(e.y + lane4));
        float w2 = *(const float*)(wb + (size_t)(e.z + lane4));
        float w3 = *(const float*)(wb + (size_t)(e.w + lane4));
        acc += w0; acc += w1; acc += w2; acc += w3;
    }
    for (; j < n; ++j)
        acc += *(const float*)(wb + (size_t)(erow[j] + lane4));
    __builtin_nontemporal_store(acc, zout + bt * WS + oslice * 64 + lane);
}

// ------- CUBA-LIF scan (hidden): consumes z, emits u64 spike mask per (b,t,oseg) -------
// Block = (b, oseg): 64 threads = 1 wave. Pipelined z loads (A/B groups of 10).
__global__ __launch_bounds__(64) void lif_ev_kernel(const float* __restrict__ z,
                                                    uint64_t* __restrict__ msk,
                                                    const float* __restrict__ cdarr,
                                                    const float* __restrict__ vdarr,
                                                    int li) {
    int bid = blockIdx.x;
    int b = bid >> 3, oseg = bid & 7;
    int lane = threadIdx.x;
    int o = oseg * 64 + lane;
    float omc = 1.0f - cdarr[li];
    float omv = 1.0f - vdarr[li];
    float cur = 0.f, volt = 0.f;
    const float* zp = z + (size_t)b * TT * CHID + o;

    float A[10], Bv[10];
    auto loadg = [&](float (&buf)[10], int g) {
        #pragma unroll
        for (int k = 0; k < 10; ++k) buf[k] = zp[(size_t)(g * 10 + k) * CHID];
    };
    auto stepg = [&](float (&buf)[10], int g) {
        #pragma unroll
        for (int k = 0; k < 10; ++k) {
            int t = g * 10 + k;
            cur  = __fadd_rn(__fmul_rn(omc, cur), buf[k]);
            volt = __fadd_rn(__fmul_rn(omv, volt), cur);
            bool s = (volt >= 1.25f);
            volt = s ? 0.f : volt;
            uint64_t bal = __ballot(s);
            if (lane == 0) msk[((size_t)b * TT + t) * 8 + oseg] = bal;
        }
    };
    loadg(A, 0);
    for (int g = 0; g < 30; g += 2) {
        if (g + 1 < 30) loadg(Bv, g + 1);
        stepg(A, g);
        if (g + 2 < 30) loadg(A, g + 2);
        if (g + 1 < 30) stepg(Bv, g + 1);
    }
}

// ------------- masks -> merged per-(b,t) u32 offset lists (shift = log2(row bytes)) -------------
// Block (b, tg): 4 waves, wave = one t. Lane parses bits [8l..8l+8) of the 512-bit mask;
// wave prefix-sum -> o-ascending merged list. Deterministic.
__global__ __launch_bounds__(256) void evbuild2_kernel(const uint64_t* __restrict__ msk,
                                                       uint32_t* __restrict__ ev,
                                                       int* __restrict__ cnt, int shift) {
    int b = blockIdx.x, tg = blockIdx.y;
    int tid = threadIdx.x, lane = tid & 63, wv = tid >> 6;
    int t = tg * TG4 + wv;
    size_t bt = (size_t)b * TT + t;
    uint64_t word = msk[bt * 8 + (lane >> 3)];
    uint32_t byte = (uint32_t)(word >> ((lane & 7) * 8)) & 0xFFu;
    int c = __popc(byte);
    int off = c;
    for (int d = 1; d < 64; d <<= 1) {
        int nn = __shfl_up(off, d, 64);
        if (lane >= d) off += nn;
    }
    int total = __shfl(off, 63, 64);
    off -= c;
    uint32_t* erow = ev + bt * EVCAP2;
    int obase = lane * 8;
    while (byte) {
        int k = __builtin_ctz(byte);
        byte &= byte - 1;
        erow[off++] = (uint32_t)(obase + k) << shift;
    }
    if (lane == 63) cnt[bt] = total;
}

// ---------------- CUBA-LIF final layer -> d_out [B][COUT][T] float, pipelined ----------------
__global__ __launch_bounds__(64) void lif_out_kernel(const float* __restrict__ z,
                                                     float* __restrict__ out,
                                                     const float* __restrict__ cdarr,
                                                     const float* __restrict__ vdarr,
                                                     int li) {
    int gid = blockIdx.x * 64 + threadIdx.x;
    if (gid >= NB * COUT) return;
    int b = gid / COUT, o = gid % COUT;
    float omc = 1.0f - cdarr[li];
    float omv = 1.0f - vdarr[li];
    float cur = 0.f, volt = 0.f;
    const float* zp = z + (size_t)b * TT * 128 + o;
    float* op = out + ((size_t)b * COUT + o) * TT;

    float A[10], Bv[10];
    auto loadg = [&](float (&buf)[10], int g) {
        #pragma unroll
        for (int k = 0; k < 10; ++k) buf[k] = zp[(size_t)(g * 10 + k) * 128];
    };
    auto stepg = [&](float (&buf)[10], int g) {
        #pragma unroll
        for (int k = 0; k < 10; ++k) {
            cur  = __fadd_rn(__fmul_rn(omc, cur), buf[k]);
            volt = __fadd_rn(__fmul_rn(omv, volt), cur);
            bool s = (volt >= 1.25f);
            volt = s ? 0.f : volt;
            op[g * 10 + k] = s ? 1.0f : 0.0f;
        }
    };
    loadg(A, 0);
    for (int g = 0; g < 30; g += 2) {
        if (g + 1 < 30) loadg(Bv, g + 1);
        stepg(A, g);
        if (g + 2 < 30) loadg(A, g + 2);
        if (g + 1 < 30) stepg(Bv, g + 1);
    }
}

extern "C" void kernel_launch(void* const* d_in, const int* in_sizes, int n_in,
                              void* d_out, int out_size, void* d_ws, size_t ws_size,
                              hipStream_t stream) {
    const float* spike = (const float*)d_in[0];
    const float* v1 = (const float*)d_in[1];
    const float* g1 = (const float*)d_in[2];
    const float* v2 = (const float*)d_in[3];
    const float* g2 = (const float*)d_in[4];
    const float* v3 = (const float*)d_in[5];
    const float* g3 = (const float*)d_in[6];
    const float* cd = (const float*)d_in[7];
    const float* vd = (const float*)d_in[8];

    // workspace layout
    float* ws   = (float*)d_ws;
    float* w1t  = ws;                            // [8192][512]
    float* w2t  = w1t + (size_t)CIN * CHID;      // [512][512]
    float* w3t  = w2t + (size_t)CHID * CHID;     // [512][128]
    float* nrm1 = w3t + (size_t)CHID * 128;      // 512
    float* nrm2 = nrm1 + 512;                    // 512
    float* nrm3 = nrm2 + 512;                    // 128
    float* zbuf = nrm3 + 128;                    // [16][300][512] (z1 then z2)
    float* z3   = zbuf + (size_t)NB * TT * CHID; // [16][300][128]
    // ev region shared across layers (sequential lifetimes); EVCAP2 <= ... both fit EVCAP2 rows? no:
    // layer1 uses EVCAP1=384 stride, layers 2/3 use EVCAP2=512 stride; allocate max.
    uint32_t* evb  = (uint32_t*)(z3 + (size_t)NB * TT * 128);      // [4800][512] max
    int*      cntb = (int*)(evb + (size_t)NB * TT * EVCAP2);       // [4800]
    uint64_t* mskb = (uint64_t*)(cntb + (size_t)NB * TT);          // [4800][8]
    size_t need = (size_t)((uint8_t*)(mskb + (size_t)NB * TT * 8) - (uint8_t*)d_ws);
    if (ws_size < need) return;  // fail loudly via wrong output rather than corrupt

    // weight prep
    norm_kernel<<<dim3(CHID), dim3(256), 0, stream>>>(v1, nrm1, CIN);
    norm_kernel<<<dim3(CHID), dim3(256), 0, stream>>>(v2, nrm2, CHID);
    norm_kernel<<<dim3(COUT), dim3(256), 0, stream>>>(v3, nrm3, CHID);
    trans_kernel<512><<<dim3(CIN / 32, CHID / 32), dim3(32, 8), 0, stream>>>(v1, g1, nrm1, w1t, CHID, CIN);
    trans_kernel<512><<<dim3(CHID / 32, CHID / 32), dim3(32, 8), 0, stream>>>(v2, g2, nrm2, w2t, CHID, CHID);
    trans_kernel<128><<<dim3(CHID / 32, 4), dim3(32, 8), 0, stream>>>(v3, g3, nrm3, w3t, COUT, CHID);

    // layer 1
    evbuild1_kernel<<<dim3(NB, NTG4), dim3(256), 0, stream>>>(spike, evb, cntb);
    zg_kernel<512, EVCAP1><<<dim3(8, NB, NTG4), dim3(256), 0, stream>>>(evb, cntb, w1t, zbuf);
    lif_ev_kernel<<<dim3(NB * 8), dim3(64), 0, stream>>>(zbuf, mskb, cd, vd, 0);
    // layer 2
    evbuild2_kernel<<<dim3(NB, NTG4), dim3(256), 0, stream>>>(mskb, evb, cntb, 11);
    zg_kernel<512, EVCAP2><<<dim3(8, NB, NTG4), dim3(256), 0, stream>>>(evb, cntb, w2t, zbuf);
    lif_ev_kernel<<<dim3(NB * 8), dim3(64), 0, stream>>>(zbuf, mskb, cd, vd, 1);
    // layer 3
    evbuild2_kernel<<<dim3(NB, NTG4), dim3(256), 0, stream>>>(mskb, evb, cntb, 9);
    zg_kernel<128, EVCAP2><<<dim3(2, NB, NTG4), dim3(256), 0, stream>>>(evb, cntb, w3t, z3);
    lif_out_kernel<<<dim3((NB * COUT + 63) / 64), dim3(64), 0, stream>>>(z3, (float*)d_out, cd, vd, 2);
}

// Round 8
// 251.553 us; speedup vs baseline: 1.4777x; 1.0647x over previous
//
#include <hip/hip_runtime.h>
#include <stdint.h>
#include <math.h>

#define NB   16
#define CIN  8192
#define CHID 512
#define COUT 100
#define TT   300
#define TG4  4
#define NTG4 75     // 300/4
#define NW1  256    // mask words per (b,t): 8192/32
#define EVCAP1 384  // merged per-(b,t) cap, layer1 (mean 164, sigma 12.7 -> 17 sigma)
#define EVCAP2 512  // layers 2/3: full range, cannot overflow

// ---------------- row norms: nrm[row] = sqrt(sum v[row][i]^2) ----------------
__global__ void norm_kernel(const float* __restrict__ v, float* __restrict__ nrm, int cin) {
    int row = blockIdx.x;
    const float* vr = v + (size_t)row * cin;
    float s = 0.f;
    for (int i = threadIdx.x; i < cin; i += 256) {
        float x = vr[i];
        s = __fadd_rn(s, __fmul_rn(x, x));
    }
    __shared__ float red[256];
    red[threadIdx.x] = s;
    __syncthreads();
    for (int off = 128; off > 0; off >>= 1) {
        if (threadIdx.x < off) red[threadIdx.x] += red[threadIdx.x + off];
        __syncthreads();
    }
    if (threadIdx.x == 0) nrm[row] = sqrtf(red[0]);
}

// ------------- transpose + weight-norm scale: wt[i][o] = (v[o][i]*g[o])/nrm[o] -------------
template<int WS>
__global__ void trans_kernel(const float* __restrict__ v, const float* __restrict__ g,
                             const float* __restrict__ nrm, float* __restrict__ wt,
                             int RO, int CI) {
    __shared__ float tile[32][33];
    int i0 = blockIdx.x * 32, o0 = blockIdx.y * 32;
    int tx = threadIdx.x, ty = threadIdx.y;
    for (int k = 0; k < 32; k += 8) {
        int o = o0 + ty + k, i = i0 + tx;
        float val = 0.f;
        if (o < RO) val = __fmul_rn(v[(size_t)o * CI + i], g[o]) / nrm[o];
        tile[ty + k][tx] = val;
    }
    __syncthreads();
    for (int k = 0; k < 32; k += 8) {
        int i = i0 + ty + k, oo = o0 + tx;
        if (oo < WS) wt[(size_t)i * WS + oo] = tile[tx][ty + k];
    }
}

// ------------- spike[b][i][t] fp32 -> bit-transposed maskT[b][t][i/32] -------------
// Block (b, itile of 64 i). Coalesced: 4 lanes x 16B = 64B (full line) per row,
// 16 rows per wave-load. LDS-staged transpose, then 128 threads emit u32 words.
__global__ __launch_bounds__(256) void mask_kernel(const float* __restrict__ spike,
                                                   uint32_t* __restrict__ maskT) {
    __shared__ uint32_t flag[64][16];  // [i_local][t_local/4], 4 u8 flags packed per word
    int b = blockIdx.x, itile = blockIdx.y;
    int tid = threadIdx.x;
    int row = tid >> 2, qc = tid & 3;
    const float* sp = spike + ((size_t)(b * CIN + itile * 64 + row)) * TT;
    for (int tc = 0; tc < 5; ++tc) {
        #pragma unroll
        for (int k = 0; k < 4; ++k) {
            int t0 = tc * 64 + k * 16 + qc * 4;
            uint32_t packed = 0;
            if (t0 + 3 < TT) {
                float4 v = *(const float4*)(sp + t0);   // 1200B row stride, 16B aligned
                packed = (v.x != 0.f ? 1u : 0u) | (v.y != 0.f ? 0x100u : 0u)
                       | (v.z != 0.f ? 0x10000u : 0u) | (v.w != 0.f ? 0x1000000u : 0u);
            }
            flag[row][k * 4 + qc] = packed;
        }
        __syncthreads();
        if (tid < 128) {
            int t_l = tid >> 1, half = tid & 1;
            int t = tc * 64 + t_l;
            if (t < TT) {
                uint32_t word = 0;
                #pragma unroll
                for (int k = 0; k < 32; ++k) {
                    uint32_t f = flag[half * 32 + k][t_l >> 2];
                    word |= (((f >> ((t_l & 3) * 8)) & 1u) << k);
                }
                maskT[((size_t)b * TT + t) * NW1 + itile * 2 + half] = word;
            }
        }
        __syncthreads();
    }
}

// ------------- maskT -> merged per-(b,t) pre-shifted u32 offset lists -------------
// One wave per (b,t). Lane parses words [4l..4l+4); wave prefix-sum of popcounts
// -> globally i-ascending merged list of byte offsets (i*2048). Deterministic.
__global__ __launch_bounds__(256) void evmerge1_kernel(const uint32_t* __restrict__ maskT,
                                                       uint32_t* __restrict__ ev,
                                                       int* __restrict__ cnt) {
    int b = blockIdx.x, tg = blockIdx.y;
    int tid = threadIdx.x, lane = tid & 63, wv = tid >> 6;
    int t = tg * TG4 + wv;
    size_t bt = (size_t)b * TT + t;
    const uint32_t* mrow = maskT + bt * NW1;
    uint4 w4 = *(const uint4*)(mrow + lane * 4);
    int c = __popc(w4.x) + __popc(w4.y) + __popc(w4.z) + __popc(w4.w);
    int off = c;
    for (int d = 1; d < 64; d <<= 1) {
        int nn = __shfl_up(off, d, 64);
        if (lane >= d) off += nn;
    }
    int total = __shfl(off, 63, 64);
    off -= c;
    uint32_t* erow = ev + bt * EVCAP1;
    uint32_t wsv[4] = {w4.x, w4.y, w4.z, w4.w};
    int base_i = lane * 128;
    #pragma unroll
    for (int wi = 0; wi < 4; ++wi) {
        uint32_t m = wsv[wi];
        while (m) {
            int bpos = __builtin_ctz(m);
            m &= m - 1;
            if (off < EVCAP1) erow[off] = (uint32_t)(base_i + wi * 32 + bpos) << 11;
            ++off;
        }
    }
    if (lane == 63) cnt[bt] = (total < EVCAP1 ? total : EVCAP1);
}

// ------------- XCD-sliced gather: z[b][t][o] = sum_{off in evlist(b,t)} wt_row(off)[o] -------------
// Grid (NSLICE, 16 b, 75 tg), 256 thr = 4 waves; wave = one t, lane = one output.
// Linear bid % 8 keyed by slice -> per-XCD wt working set (2MB layer1) stays L2-resident.
// Entries pre-shifted byte offsets; walk j-ascending == i-ascending (exact sums).
template<int WS, int EVCAP>
__global__ __launch_bounds__(256) void zg_kernel(const uint32_t* __restrict__ ev,
                                                 const int* __restrict__ cnt,
                                                 const float* __restrict__ wt,
                                                 float* __restrict__ zout) {
    int oslice = blockIdx.x, b = blockIdx.y, tg = blockIdx.z;
    int tid = threadIdx.x, lane = tid & 63, wv = tid >> 6;
    int t = tg * TG4 + wv;
    size_t bt = (size_t)b * TT + t;
    const uint32_t* erow = ev + bt * EVCAP;
    int n = cnt[bt];
    const char* wb = (const char*)wt + (size_t)oslice * 256;  // uniform (SGPR) base
    uint32_t lane4 = (uint32_t)lane * 4u;
    float acc = 0.f;
    int j = 0;
    for (; j + 16 <= n; j += 16) {
        uint4 eA = *(const uint4*)(erow + j);
        uint4 eB = *(const uint4*)(erow + j + 4);
        uint4 eC = *(const uint4*)(erow + j + 8);
        uint4 eD = *(const uint4*)(erow + j + 12);
        float w0  = *(const float*)(wb + (size_t)(eA.x + lane4));
        float w1  = *(const float*)(wb + (size_t)(eA.y + lane4));
        float w2  = *(const float*)(wb + (size_t)(eA.z + lane4));
        float w3  = *(const float*)(wb + (size_t)(eA.w + lane4));
        float w4  = *(const float*)(wb + (size_t)(eB.x + lane4));
        float w5  = *(const float*)(wb + (size_t)(eB.y + lane4));
        float w6  = *(const float*)(wb + (size_t)(eB.z + lane4));
        float w7  = *(const float*)(wb + (size_t)(eB.w + lane4));
        float w8  = *(const float*)(wb + (size_t)(eC.x + lane4));
        float w9  = *(const float*)(wb + (size_t)(eC.y + lane4));
        float w10 = *(const float*)(wb + (size_t)(eC.z + lane4));
        float w11 = *(const float*)(wb + (size_t)(eC.w + lane4));
        float w12 = *(const float*)(wb + (size_t)(eD.x + lane4));
        float w13 = *(const float*)(wb + (size_t)(eD.y + lane4));
        float w14 = *(const float*)(wb + (size_t)(eD.z + lane4));
        float w15 = *(const float*)(wb + (size_t)(eD.w + lane4));
        acc += w0;  acc += w1;  acc += w2;  acc += w3;
        acc += w4;  acc += w5;  acc += w6;  acc += w7;
        acc += w8;  acc += w9;  acc += w10; acc += w11;
        acc += w12; acc += w13; acc += w14; acc += w15;
    }
    for (; j + 4 <= n; j += 4) {
        uint4 e = *(const uint4*)(erow + j);
        float w0 = *(const float*)(wb + (size_t)(e.x + lane4));
        float w1 = *(const float*)(wb + (size_t)(e.y + lane4));
        float w2 = *(const float*)(wb + (size_t)(e.z + lane4));
        float w3 = *(const float*)(wb + (size_t)(e.w + lane4));
        acc += w0; acc += w1; acc += w2; acc += w3;
    }
    for (; j < n; ++j)
        acc += *(const float*)(wb + (size_t)(erow[j] + lane4));
    __builtin_nontemporal_store(acc, zout + bt * WS + oslice * 64 + lane);
}

// ------- CUBA-LIF scan (hidden): consumes z, emits u64 spike mask per (b,t,oseg) -------
__global__ __launch_bounds__(64) void lif_ev_kernel(const float* __restrict__ z,
                                                    uint64_t* __restrict__ msk,
                                                    const float* __restrict__ cdarr,
                                                    const float* __restrict__ vdarr,
                                                    int li) {
    int bid = blockIdx.x;
    int b = bid >> 3, oseg = bid & 7;
    int lane = threadIdx.x;
    int o = oseg * 64 + lane;
    float omc = 1.0f - cdarr[li];
    float omv = 1.0f - vdarr[li];
    float cur = 0.f, volt = 0.f;
    const float* zp = z + (size_t)b * TT * CHID + o;

    float A[10], Bv[10];
    auto loadg = [&](float (&buf)[10], int g) {
        #pragma unroll
        for (int k = 0; k < 10; ++k) buf[k] = zp[(size_t)(g * 10 + k) * CHID];
    };
    auto stepg = [&](float (&buf)[10], int g) {
        #pragma unroll
        for (int k = 0; k < 10; ++k) {
            int t = g * 10 + k;
            cur  = __fadd_rn(__fmul_rn(omc, cur), buf[k]);
            volt = __fadd_rn(__fmul_rn(omv, volt), cur);
            bool s = (volt >= 1.25f);
            volt = s ? 0.f : volt;
            uint64_t bal = __ballot(s);
            if (lane == 0) msk[((size_t)b * TT + t) * 8 + oseg] = bal;
        }
    };
    loadg(A, 0);
    for (int g = 0; g < 30; g += 2) {
        if (g + 1 < 30) loadg(Bv, g + 1);
        stepg(A, g);
        if (g + 2 < 30) loadg(A, g + 2);
        if (g + 1 < 30) stepg(Bv, g + 1);
    }
}

// ------------- masks -> merged per-(b,t) u32 offset lists (shift = log2(row bytes)) -------------
__global__ __launch_bounds__(256) void evbuild2_kernel(const uint64_t* __restrict__ msk,
                                                       uint32_t* __restrict__ ev,
                                                       int* __restrict__ cnt, int shift) {
    int b = blockIdx.x, tg = blockIdx.y;
    int tid = threadIdx.x, lane = tid & 63, wv = tid >> 6;
    int t = tg * TG4 + wv;
    size_t bt = (size_t)b * TT + t;
    uint64_t word = msk[bt * 8 + (lane >> 3)];
    uint32_t byte = (uint32_t)(word >> ((lane & 7) * 8)) & 0xFFu;
    int c = __popc(byte);
    int off = c;
    for (int d = 1; d < 64; d <<= 1) {
        int nn = __shfl_up(off, d, 64);
        if (lane >= d) off += nn;
    }
    int total = __shfl(off, 63, 64);
    off -= c;
    uint32_t* erow = ev + bt * EVCAP2;
    int obase = lane * 8;
    while (byte) {
        int k = __builtin_ctz(byte);
        byte &= byte - 1;
        erow[off++] = (uint32_t)(obase + k) << shift;
    }
    if (lane == 63) cnt[bt] = total;
}

// ---------------- CUBA-LIF final layer -> d_out [B][COUT][T] float, pipelined ----------------
__global__ __launch_bounds__(64) void lif_out_kernel(const float* __restrict__ z,
                                                     float* __restrict__ out,
                                                     const float* __restrict__ cdarr,
                                                     const float* __restrict__ vdarr,
                                                     int li) {
    int gid = blockIdx.x * 64 + threadIdx.x;
    if (gid >= NB * COUT) return;
    int b = gid / COUT, o = gid % COUT;
    float omc = 1.0f - cdarr[li];
    float omv = 1.0f - vdarr[li];
    float cur = 0.f, volt = 0.f;
    const float* zp = z + (size_t)b * TT * 128 + o;
    float* op = out + ((size_t)b * COUT + o) * TT;

    float A[10], Bv[10];
    auto loadg = [&](float (&buf)[10], int g) {
        #pragma unroll
        for (int k = 0; k < 10; ++k) buf[k] = zp[(size_t)(g * 10 + k) * 128];
    };
    auto stepg = [&](float (&buf)[10], int g) {
        #pragma unroll
        for (int k = 0; k < 10; ++k) {
            cur  = __fadd_rn(__fmul_rn(omc, cur), buf[k]);
            volt = __fadd_rn(__fmul_rn(omv, volt), cur);
            bool s = (volt >= 1.25f);
            volt = s ? 0.f : volt;
            op[g * 10 + k] = s ? 1.0f : 0.0f;
        }
    };
    loadg(A, 0);
    for (int g = 0; g < 30; g += 2) {
        if (g + 1 < 30) loadg(Bv, g + 1);
        stepg(A, g);
        if (g + 2 < 30) loadg(A, g + 2);
        if (g + 1 < 30) stepg(Bv, g + 1);
    }
}

extern "C" void kernel_launch(void* const* d_in, const int* in_sizes, int n_in,
                              void* d_out, int out_size, void* d_ws, size_t ws_size,
                              hipStream_t stream) {
    const float* spike = (const float*)d_in[0];
    const float* v1 = (const float*)d_in[1];
    const float* g1 = (const float*)d_in[2];
    const float* v2 = (const float*)d_in[3];
    const float* g2 = (const float*)d_in[4];
    const float* v3 = (const float*)d_in[5];
    const float* g3 = (const float*)d_in[6];
    const float* cd = (const float*)d_in[7];
    const float* vd = (const float*)d_in[8];

    // workspace layout
    float* ws   = (float*)d_ws;
    float* w1t  = ws;                            // [8192][512]
    float* w2t  = w1t + (size_t)CIN * CHID;      // [512][512]
    float* w3t  = w2t + (size_t)CHID * CHID;     // [512][128]
    float* nrm1 = w3t + (size_t)CHID * 128;      // 512
    float* nrm2 = nrm1 + 512;                    // 512
    float* nrm3 = nrm2 + 512;                    // 128
    float* zbuf = nrm3 + 128;                    // [16][300][512] (z1 then z2)
    float* z3   = zbuf + (size_t)NB * TT * CHID; // [16][300][128]
    uint32_t* evb   = (uint32_t*)(z3 + (size_t)NB * TT * 128);     // [4800][EVCAP2] max stride
    int*      cntb  = (int*)(evb + (size_t)NB * TT * EVCAP2);      // [4800]
    uint64_t* mskb  = (uint64_t*)(cntb + (size_t)NB * TT);         // [4800][8]
    uint32_t* maskT = (uint32_t*)(mskb + (size_t)NB * TT * 8);     // [4800][256]
    size_t need = (size_t)((uint8_t*)(maskT + (size_t)NB * TT * NW1) - (uint8_t*)d_ws);
    if (ws_size < need) return;  // fail loudly via wrong output rather than corrupt

    // weight prep
    norm_kernel<<<dim3(CHID), dim3(256), 0, stream>>>(v1, nrm1, CIN);
    norm_kernel<<<dim3(CHID), dim3(256), 0, stream>>>(v2, nrm2, CHID);
    norm_kernel<<<dim3(COUT), dim3(256), 0, stream>>>(v3, nrm3, CHID);
    trans_kernel<512><<<dim3(CIN / 32, CHID / 32), dim3(32, 8), 0, stream>>>(v1, g1, nrm1, w1t, CHID, CIN);
    trans_kernel<512><<<dim3(CHID / 32, CHID / 32), dim3(32, 8), 0, stream>>>(v2, g2, nrm2, w2t, CHID, CHID);
    trans_kernel<128><<<dim3(CHID / 32, 4), dim3(32, 8), 0, stream>>>(v3, g3, nrm3, w3t, COUT, CHID);

    // layer 1: coalesced bit-transpose -> merged event lists -> XCD-sliced gather
    mask_kernel<<<dim3(NB, CIN / 64), dim3(256), 0, stream>>>(spike, maskT);
    evmerge1_kernel<<<dim3(NB, NTG4), dim3(256), 0, stream>>>(maskT, evb, cntb);
    zg_kernel<512, EVCAP1><<<dim3(8, NB, NTG4), dim3(256), 0, stream>>>(evb, cntb, w1t, zbuf);
    lif_ev_kernel<<<dim3(NB * 8), dim3(64), 0, stream>>>(zbuf, mskb, cd, vd, 0);
    // layer 2
    evbuild2_kernel<<<dim3(NB, NTG4), dim3(256), 0, stream>>>(mskb, evb, cntb, 11);
    zg_kernel<512, EVCAP2><<<dim3(8, NB, NTG4), dim3(256), 0, stream>>>(evb, cntb, w2t, zbuf);
    lif_ev_kernel<<<dim3(NB * 8), dim3(64), 0, stream>>>(zbuf, mskb, cd, vd, 1);
    // layer 3
    evbuild2_kernel<<<dim3(NB, NTG4), dim3(256), 0, stream>>>(mskb, evb, cntb, 9);
    zg_kernel<128, EVCAP2><<<dim3(2, NB, NTG4), dim3(256), 0, stream>>>(evb, cntb, w3t, z3);
    lif_out_kernel<<<dim3((NB * COUT + 63) / 64), dim3(64), 0, stream>>>(z3, (float*)d_out, cd, vd, 2);
}